// Round 13
// baseline (638.329 us; speedup 1.0000x reference)
//
#include <hip/hip_runtime.h>

#define BB 32
#define NITER 15
// Exit when per-batch ||u-v||_2 < 3e-5 (split-bf16 noise floor ~1.5e-5 > ref's 1e-6)
#define EPS2 9e-10f   // (3e-5)^2

typedef unsigned short u16;
typedef unsigned int   u32;
typedef __attribute__((ext_vector_type(8))) short  bf16x8;  // 8 bf16 = 4 VGPR (MFMA A/B frag)
typedef __attribute__((ext_vector_type(4))) float  f32x4;   // MFMA C/D frag
typedef __attribute__((ext_vector_type(8))) u16    u16x8;
typedef __attribute__((ext_vector_type(4))) u16    u16x4;

#define CPIT 36   // u16 pitch for 32-wide k chunks (72B rows -> 2-way bank alias, free)

__device__ __forceinline__ u16 f2bf(float x){            // RNE fp32 -> bf16 bits
  unsigned u = __float_as_uint(x);
  return (u16)((u + 0x7FFFu + ((u>>16)&1u)) >> 16);
}
__device__ __forceinline__ float bf2f(u16 h){ return __uint_as_float(((unsigned)h)<<16); }

// ============ init: v = 1, vT planes = (1,0), flag = 1, ctr = 0 ============
__global__ __launch_bounds__(256) void k_initv(float* __restrict__ v, u16* __restrict__ vTp,
                                               int* __restrict__ flag, unsigned* __restrict__ ctr){
  int gid = blockIdx.x*256 + threadIdx.x;               // grid 512
  #pragma unroll
  for (int i = 0; i < 4; ++i){
    int e = gid*4 + i;
    if (e < BB*16384) v[e] = 1.0f;
  }
  #pragma unroll
  for (int i = 0; i < 8; ++i){
    int e = gid*8 + i;
    if (e < BB*32768) vTp[e] = ((e>>14)&1) ? (u16)0 : (u16)0x3F80;  // hi plane=1.0, lo=0
  }
  if (gid == 0){ *flag = 1; *ctr = 0u; }
}

// ============ prep: split (no transpose)  in[128][512] -> planes [128][512] ============
__global__ __launch_bounds__(256) void k_prep(const float* __restrict__ G1, const float* __restrict__ H1,
                                              const float* __restrict__ G2, const float* __restrict__ H2,
                                              u16* __restrict__ P1p, u16* __restrict__ P2p){
  const int t = blockIdx.z, b = blockIdx.y;
  const float* src = (t==0?G1: t==1?H1: t==2?G2:H2) + (size_t)b*65536;
  u16* dst = (t<2? P1p : P2p) + ((size_t)((t&1)*BB + b))*2*65536;
  const int e0 = (blockIdx.x*256 + threadIdx.x)*8;
  float4 v0 = *(const float4*)(src + e0);
  float4 v1 = *(const float4*)(src + e0 + 4);
  float xs[8] = {v0.x,v0.y,v0.z,v0.w,v1.x,v1.y,v1.z,v1.w};
  u16x8 h, l;
  #pragma unroll
  for (int i = 0; i < 8; ++i){
    u16 hi = f2bf(xs[i]); h[i] = hi; l[i] = f2bf(xs[i] - bf2f(hi));
  }
  *(u16x8*)(dst + e0) = h;
  *(u16x8*)(dst + 65536 + e0) = l;
}

// ============ prepT: transpose + split  in[128][512] -> planes [512][128] ============
__global__ __launch_bounds__(256) void k_prepT(const float* __restrict__ H1, const float* __restrict__ G1,
                                               const float* __restrict__ H2, const float* __restrict__ G2,
                                               u16* __restrict__ Q1T, u16* __restrict__ Q2T){
  const int t = blockIdx.z & 3, b = blockIdx.z >> 2;
  const float* src = (t==0?H1: t==1?G1: t==2?H2:G2) + (size_t)b*65536;   // [128 n][512 m]
  u16* dst = (t<2? Q1T : Q2T) + ((size_t)((t&1)*BB + b))*2*65536;        // [512 m][128 n]
  const int mt = blockIdx.x*32, nt = blockIdx.y*32;
  __shared__ float ts[32][33];
  const int r = threadIdx.x>>3, c4 = (threadIdx.x&7)*4;
  float4 vv = *(const float4*)(src + (size_t)(nt+r)*512 + mt + c4);
  ts[r][c4+0]=vv.x; ts[r][c4+1]=vv.y; ts[r][c4+2]=vv.z; ts[r][c4+3]=vv.w;
  __syncthreads();
  u16x4 h, l;
  #pragma unroll
  for (int i = 0; i < 4; ++i){
    float x = ts[c4+i][r];
    u16 hi = f2bf(x); h[i] = hi; l[i] = f2bf(x - bf2f(hi));
  }
  size_t o = (size_t)(mt + r)*128 + nt + c4;
  *(u16x4*)(dst + o) = h;
  *(u16x4*)(dst + 65536 + o) = l;
}

// ============ prep MqI: transpose + split-pack Mq[b][m][q] -> u32 (hi | lo<<16) at [b][q][m] ============
__global__ __launch_bounds__(256) void k_prepM(const float* __restrict__ Mq, unsigned* __restrict__ MqI){
  const int b = blockIdx.z;
  const float* src = Mq + (size_t)b*262144;
  unsigned* D = MqI + (size_t)b*262144;
  const int mt = blockIdx.x*32, qt = blockIdx.y*32;
  __shared__ float ts[32][33];
  const int r = threadIdx.x>>3, c4 = (threadIdx.x&7)*4;
  float4 vv = *(const float4*)(src + (size_t)(mt+r)*512 + qt + c4);
  ts[r][c4+0]=vv.x; ts[r][c4+1]=vv.y; ts[r][c4+2]=vv.z; ts[r][c4+3]=vv.w;
  __syncthreads();
  uint4 pk;
  unsigned pks[4];
  #pragma unroll
  for (int i = 0; i < 4; ++i){
    float x = ts[c4+i][r];
    u16 hi = f2bf(x);
    pks[i] = (unsigned)hi | ((unsigned)f2bf(x - bf2f(hi)) << 16);
  }
  pk.x=pks[0]; pk.y=pks[1]; pk.z=pks[2]; pk.w=pks[3];
  *(uint4*)(D + (size_t)(qt + r)*512 + mt + c4) = pk;
}

// ============ S0: x1[m][p] = sum_n Q1T[m][n]*vT[p][n]   grid(512): (fb, mb of 64 rows) ============
__global__ __launch_bounds__(256) void k_s0(const u16* __restrict__ Q1T,
                                            const u16* __restrict__ vTp,
                                            u16* __restrict__ x1p,
                                            const int* __restrict__ flag){
  if (*flag == 0) return;
  const int flat = blockIdx.x;
  const int work = (flat & 7)*64 + (flat >> 3);
  const int fb = work >> 3, mb = work & 7, b = fb & 31;

  const u16* Ah = Q1T + (size_t)fb*131072 + (size_t)mb*8192;   // [64 m][128 n]
  const u16* Al = Ah + 65536;
  const u16* Bh = vTp + (size_t)b*32768;                       // [128 p][128 n]
  const u16* Bl = Bh + 16384;

  const int tid = threadIdx.x;
  const int wid = tid>>6, lane = tid&63;
  const int wn = wid*16;                    // wave owns 16 m rows x 128 p
  const int l15 = lane&15, g = lane>>4;

  __shared__ __align__(16) u16 smA[2][64*40];
  __shared__ __align__(16) u16 smB[2][128*40];

  f32x4 acc[8];
  #pragma unroll
  for (int j=0;j<8;++j) acc[j] = (f32x4){0.f,0.f,0.f,0.f};

  for (int kt = 0; kt < 128; kt += 32){
    { int row = tid>>2, seg = tid&3;
      size_t go = (size_t)row*128 + kt + seg*8;
      *(u16x8*)&smA[0][row*40 + seg*8] = *(const u16x8*)(Ah + go);
      *(u16x8*)&smA[1][row*40 + seg*8] = *(const u16x8*)(Al + go);
    }
    #pragma unroll
    for (int i = 0; i < 2; ++i){
      int c = tid + i*256, row = c>>2, seg = c&3;
      size_t go = (size_t)row*128 + kt + seg*8;
      *(u16x8*)&smB[0][row*40 + seg*8] = *(const u16x8*)(Bh + go);
      *(u16x8*)&smB[1][row*40 + seg*8] = *(const u16x8*)(Bl + go);
    }
    __syncthreads();
    bf16x8 ah = *(const bf16x8*)&smA[0][(wn + l15)*40 + g*8];
    bf16x8 al = *(const bf16x8*)&smA[1][(wn + l15)*40 + g*8];
    #pragma unroll
    for (int j=0;j<8;++j){
      bf16x8 bh = *(const bf16x8*)&smB[0][(j*16 + l15)*40 + g*8];
      bf16x8 bl = *(const bf16x8*)&smB[1][(j*16 + l15)*40 + g*8];
      acc[j] = __builtin_amdgcn_mfma_f32_16x16x32_bf16(ah, bh, acc[j], 0,0,0);
      acc[j] = __builtin_amdgcn_mfma_f32_16x16x32_bf16(al, bh, acc[j], 0,0,0);
      acc[j] = __builtin_amdgcn_mfma_f32_16x16x32_bf16(ah, bl, acc[j], 0,0,0);
    }
    __syncthreads();
  }
  u16* Ch = x1p + (size_t)fb*131072;
  u16* Cl = Ch + 65536;
  #pragma unroll
  for (int j=0;j<8;++j)
    #pragma unroll
    for (int r=0;r<4;++r){
      int ro = mb*64 + wn + g*4 + r, co = j*16 + l15;
      float x = acc[j][r];
      u16 hi = f2bf(x);
      Ch[(size_t)ro*128 + co] = hi;
      Cl[(size_t)ro*128 + co] = f2bf(x - bf2f(hi));
    }
}

// ============ fused S1+S2+S3 helpers ============
// stage 128 rows x 32 u16 k-chunk (hi+lo planes), row stride gs, k offset kOff
__device__ __forceinline__ void stg128(const u16* __restrict__ sH, const u16* __restrict__ sL,
                                       int gs, int kOff, u16 (* __restrict__ buf)[128*CPIT], int tid){
  #pragma unroll
  for (int i = 0; i < 2; ++i){
    int c = tid + i*256, row = c>>2, seg = c&3;
    size_t go = (size_t)row*gs + kOff + seg*8;
    *(u16x8*)&buf[0][row*CPIT + seg*8] = *(const u16x8*)(sH + go);
    *(u16x8*)&buf[1][row*CPIT + seg*8] = *(const u16x8*)(sL + go);
  }
}
// stage 64 rows x 32 u16 (one chunk/thread)
__device__ __forceinline__ void stg64(const u16* __restrict__ sH, const u16* __restrict__ sL,
                                      int gs, int kOff, u16 (* __restrict__ buf)[128*CPIT], int tid){
  int row = tid>>2, seg = tid&3;
  size_t go = (size_t)row*gs + kOff + seg*8;
  *(u16x8*)&buf[0][row*CPIT + seg*8] = *(const u16x8*)(sH + go);
  *(u16x8*)&buf[1][row*CPIT + seg*8] = *(const u16x8*)(sL + go);
}

// y-phase MFMA: acc[2][8], A rows wq+i*16 (32/wave covers 128), B rows j*16 (128)
__device__ __forceinline__ void mmc2(f32x4 acc[2][8],
                                     const u16 (* __restrict__ A)[128*CPIT],
                                     const u16 (* __restrict__ B)[128*CPIT],
                                     int wq, int l15, int g){
  bf16x8 ah[2], al[2];
  #pragma unroll
  for (int i = 0; i < 2; ++i){
    int r = wq + i*16 + l15;
    ah[i] = *(const bf16x8*)&A[0][r*CPIT + g*8];
    al[i] = *(const bf16x8*)&A[1][r*CPIT + g*8];
  }
  #pragma unroll
  for (int j = 0; j < 8; ++j){
    bf16x8 bh = *(const bf16x8*)&B[0][(j*16 + l15)*CPIT + g*8];
    bf16x8 bl = *(const bf16x8*)&B[1][(j*16 + l15)*CPIT + g*8];
    #pragma unroll
    for (int i = 0; i < 2; ++i){
      acc[i][j] = __builtin_amdgcn_mfma_f32_16x16x32_bf16(ah[i], bh, acc[i][j], 0,0,0);
      acc[i][j] = __builtin_amdgcn_mfma_f32_16x16x32_bf16(al[i], bh, acc[i][j], 0,0,0);
      acc[i][j] = __builtin_amdgcn_mfma_f32_16x16x32_bf16(ah[i], bl, acc[i][j], 0,0,0);
    }
  }
}
// z-phase MFMA: acc[8], A rows wn (16/wave covers 64), B rows j*16 (128)
__device__ __forceinline__ void mmc1(f32x4 acc[8],
                                     const u16 (* __restrict__ A)[128*CPIT],
                                     const u16 (* __restrict__ B)[128*CPIT],
                                     int wn, int l15, int g){
  bf16x8 ah = *(const bf16x8*)&A[0][(wn + l15)*CPIT + g*8];
  bf16x8 al = *(const bf16x8*)&A[1][(wn + l15)*CPIT + g*8];
  #pragma unroll
  for (int j = 0; j < 8; ++j){
    bf16x8 bh = *(const bf16x8*)&B[0][(j*16 + l15)*CPIT + g*8];
    bf16x8 bl = *(const bf16x8*)&B[1][(j*16 + l15)*CPIT + g*8];
    acc[j] = __builtin_amdgcn_mfma_f32_16x16x32_bf16(ah, bh, acc[j], 0,0,0);
    acc[j] = __builtin_amdgcn_mfma_f32_16x16x32_bf16(al, bh, acc[j], 0,0,0);
    acc[j] = __builtin_amdgcn_mfma_f32_16x16x32_bf16(ah, bl, acc[j], 0,0,0);
  }
}

// ============ k_ys2 (S1+S2+S3 fused): per (fb,qblk,nh) -> z2 partial chunk; y,z1 never global ============
// grid(512) = 2 blocks/CU (LDS 36.9KB). y-phase duplicated across nh (MFMA is cheap, traffic isn't).
__global__ __launch_bounds__(256) void k_ys2(const u16* __restrict__ Q2T,
                                             const u16* __restrict__ x1p,
                                             const u16* __restrict__ P1p,
                                             const u16* __restrict__ P2p,
                                             const unsigned* __restrict__ MqI,
                                             float* __restrict__ z2p,
                                             const int* __restrict__ flag){
  if (*flag == 0) return;
  const int flat = blockIdx.x;
  const int work = (flat & 7)*64 + (flat >> 3);     // bijective XCD swizzle
  const int fb = work >> 3, qblk = (work >> 1) & 3, nh = work & 1, b = fb & 31;

  const int tid = threadIdx.x;
  const int wid = tid>>6, lane = tid&63;
  const int wq = wid*32;                            // y-phase: wave owns 32 q rows
  const int wn = wid*16;                            // z/S3-phase: wave owns 16 n rows
  const int l15 = lane&15, g = lane>>4;

  __shared__ __align__(16) u16 bufA[2][128*CPIT];
  __shared__ __align__(16) u16 bufB[2][128*CPIT];

  const u16* Qh = Q2T + (size_t)fb*131072 + (size_t)qblk*16384;  // [128 q][128 p]
  const u16* Ql = Qh + 65536;
  const unsigned* Mqb = MqI + (size_t)b*262144;
  const u16* P1h = P1p + (size_t)fb*131072 + (size_t)nh*32768;   // [64 n][512 m] rows nh*64..
  const u16* P1l = P1h + 65536;

  f32x4 zacc[8];
  #pragma unroll
  for (int j=0;j<8;++j) zacc[j] = (f32x4){0.f,0.f,0.f,0.f};

  for (int mblk = 0; mblk < 4; ++mblk){
    const u16* Xh = x1p + (size_t)fb*131072 + (size_t)mblk*16384; // [128 m][128 p]
    const u16* Xl = Xh + 65536;

    // ---- y[q][m] = sum_p Q2T[q][p]*x1[m][p], k-chunks of 32 p ascending ----
    f32x4 yacc[2][8];
    #pragma unroll
    for (int i=0;i<2;++i)
      #pragma unroll
      for (int j=0;j<8;++j) yacc[i][j] = (f32x4){0.f,0.f,0.f,0.f};
    for (int pc = 0; pc < 4; ++pc){
      stg128(Qh, Ql, 128, pc*32, bufA, tid);
      stg128(Xh, Xl, 128, pc*32, bufB, tid);
      __syncthreads();
      mmc2(yacc, bufA, bufB, wq, l15, g);
      __syncthreads();
    }

    // ---- per 32-m subchunk: y*Mq rounded -> bufA; stage P1 chunk -> bufB; zacc += P1.y^T ----
    for (int mc = 0; mc < 4; ++mc){
      #pragma unroll
      for (int jj = 0; jj < 2; ++jj){
        int j = mc*2 + jj;
        #pragma unroll
        for (int i = 0; i < 2; ++i)
          #pragma unroll
          for (int r = 0; r < 4; ++r){
            int ql = wq + i*16 + g*4 + r;          // local q
            int ml = j*16 + l15;                   // local m
            unsigned mq = Mqb[(size_t)(qblk*128 + ql)*512 + mblk*128 + ml];
            float mf = bf2f((u16)(mq & 0xFFFFu)) + bf2f((u16)(mq >> 16));
            float y = yacc[i][j][r] * mf;
            u16 hi = f2bf(y);
            bufA[0][ql*CPIT + jj*16 + l15] = hi;
            bufA[1][ql*CPIT + jj*16 + l15] = f2bf(y - bf2f(hi));
          }
      }
      stg64(P1h, P1l, 512, mblk*128 + mc*32, bufB, tid);
      __syncthreads();
      mmc1(zacc, bufB, bufA, wn, l15, g);          // A=P1 rows n(64), B=y rows q(128), k=m
      __syncthreads();
    }
  }

  // ---- S3 tail: round zacc -> z1 chunks; z2[n][p] += z1 . P2 over q-chunks of 32 ----
  const u16* P2h = P2p + (size_t)fb*131072 + (size_t)qblk*128;   // [128 p][512 q] col slice
  const u16* P2l = P2h + 65536;
  f32x4 z2a[8];
  #pragma unroll
  for (int j=0;j<8;++j) z2a[j] = (f32x4){0.f,0.f,0.f,0.f};

  #pragma unroll
  for (int qc = 0; qc < 4; ++qc){
    #pragma unroll
    for (int jj = 0; jj < 2; ++jj)
      #pragma unroll
      for (int r = 0; r < 4; ++r){
        int n = wn + g*4 + r;
        float x = zacc[qc*2 + jj][r];
        u16 hi = f2bf(x);
        bufA[0][n*CPIT + jj*16 + l15] = hi;
        bufA[1][n*CPIT + jj*16 + l15] = f2bf(x - bf2f(hi));
      }
    stg128(P2h, P2l, 512, qc*32, bufB, tid);
    __syncthreads();
    mmc1(z2a, bufA, bufB, wn, l15, g);             // A=z1 rows n(64), B=P2 rows p(128), k=q
    __syncthreads();
  }

  float* Cb = z2p + ((size_t)fb*4 + qblk)*16384;
  #pragma unroll
  for (int j=0;j<8;++j)
    #pragma unroll
    for (int r=0;r<4;++r){
      int ro = nh*64 + wn + g*4 + r, co = j*16 + l15;
      Cb[(size_t)ro*128 + co] = z2a[j][r];
    }
}

// ============ fused: t = 0.5*sum(z2p) + Mp.*v ; nrm ; u ; diff ; v=u ; vT planes ; flag ============
// grid(32), block(1024)
__global__ __launch_bounds__(1024) void k_nf(const float* __restrict__ z2p,
                                             const float* __restrict__ Mp,
                                             float* __restrict__ v,
                                             u16* __restrict__ vTp,
                                             float* __restrict__ diff2,
                                             int* __restrict__ flag,
                                             unsigned* __restrict__ ctr){
  if (*flag == 0) return;
  const int b = blockIdx.x, tid = threadIdx.x;
  const size_t base = (size_t)b*16384;
  __shared__ float sred[1024];
  __shared__ float su[128][129];

  float tv[16], vv[16];
  float n2 = 0.f;
  #pragma unroll
  for (int i = 0; i < 16; ++i){
    int e = tid + i*1024;
    float z = 0.f;
    #pragma unroll
    for (int f = 0; f < 2; ++f)
      #pragma unroll
      for (int cc = 0; cc < 4; ++cc)
        z += z2p[(((size_t)f*BB + b)*4 + cc)*16384 + e];
    vv[i] = v[base + e];
    tv[i] = 0.5f*z + Mp[base + e]*vv[i];
    n2 += tv[i]*tv[i];
  }
  sred[tid] = n2; __syncthreads();
  for (int s = 512; s > 0; s >>= 1){ if (tid < s) sred[tid] += sred[tid+s]; __syncthreads(); }
  float nrm2 = sred[0];
  __syncthreads();

  float rn = (nrm2 == 0.f) ? 0.f : 1.0f / sqrtf(nrm2);
  float d2 = 0.f;
  #pragma unroll
  for (int i = 0; i < 16; ++i){
    int e = tid + i*1024;
    float u = tv[i] * rn;
    float d = u - vv[i];
    d2 += d*d;
    v[base + e] = u;
    su[e>>7][e&127] = u;
  }
  sred[tid] = d2; __syncthreads();
  for (int s = 512; s > 0; s >>= 1){ if (tid < s) sred[tid] += sred[tid+s]; __syncthreads(); }

  u16* Ch = vTp + (size_t)b*32768;
  u16* Cl = Ch + 16384;
  #pragma unroll
  for (int i = 0; i < 16; ++i){
    int e = tid + i*1024;                  // e = p*128 + n
    float x = su[e & 127][e >> 7];
    u16 hi = f2bf(x);
    Ch[e] = hi;
    Cl[e] = f2bf(x - bf2f(hi));
  }

  if (tid == 0){
    diff2[b] = sred[0];
    __threadfence();
    unsigned old = atomicAdd(ctr, 1u);
    if (old == (unsigned)(BB - 1)){
      __threadfence();
      int any = 0;
      #pragma unroll
      for (int j = 0; j < BB; ++j) any |= (diff2[j] >= EPS2) ? 1 : 0;
      if (!any) *flag = 0;
      *ctr = 0u;
    }
  }
}

extern "C" void kernel_launch(void* const* d_in, const int* in_sizes, int n_in,
                              void* d_out, int out_size, void* d_ws, size_t ws_size,
                              hipStream_t stream) {
  const float* Mp = (const float*)d_in[0];
  const float* Mq = (const float*)d_in[1];
  const float* G1 = (const float*)d_in[2];
  const float* G2 = (const float*)d_in[3];
  const float* H1 = (const float*)d_in[4];
  const float* H2 = (const float*)d_in[5];
  float* v = (float*)d_out;

  u16* Q1T = (u16*)d_ws;                   //  [64 fb][2][512][128]
  u16* Q2T = Q1T + 8388608;                //  [64 fb][2][512][128]
  u16* P1p = Q2T + 8388608;                //  [64 fb][2][128][512]
  u16* P2p = P1p + 8388608;                //  [64 fb][2][128][512]
  u16* x1p = P2p + 8388608;                //  [64 fb][2][512][128]
  u16* vTp = x1p + 8388608;                //  [32 b][2][128][128]
  unsigned* MqI = (unsigned*)(vTp + 1048576); // [32][512][512] u32 (hi|lo<<16)
  float* z2p  = (float*)(MqI + 8388608);   //  [64 fb][4 c][128][128]
  float* diff2 = z2p + 4194304;            //  [32]
  int* flag = (int*)(diff2 + 32);
  unsigned* ctr = (unsigned*)(flag + 1);

  k_initv<<<dim3(512), 256, 0, stream>>>(v, vTp, flag, ctr);
  k_prep <<<dim3(32, 32, 4),  256, 0, stream>>>(G1, H1, G2, H2, P1p, P2p);
  k_prepT<<<dim3(16, 4, 128), 256, 0, stream>>>(H1, G1, H2, G2, Q1T, Q2T);
  k_prepM<<<dim3(16, 16, 32), 256, 0, stream>>>(Mq, MqI);

  for (int it = 0; it < NITER; ++it) {
    k_s0 <<<dim3(512), 256, 0, stream>>>(Q1T, vTp, x1p, flag);
    k_ys2<<<dim3(512), 256, 0, stream>>>(Q2T, x1p, P1p, P2p, MqI, z2p, flag);
    k_nf <<<dim3(32), 1024, 0, stream>>>(z2p, Mp, v, vTp, diff2, flag, ctr);
  }
}

// Round 14
// 356.627 us; speedup vs baseline: 1.7899x; 1.7899x over previous
//
#include <hip/hip_runtime.h>

#define BB 32
#define NITER 15
// Exit when per-batch ||u-v||_2 < 3e-5 (split-bf16 noise floor ~1.5e-5 > ref's 1e-6)
#define EPS2 9e-10f   // (3e-5)^2

typedef unsigned short u16;
typedef unsigned int   u32;
typedef __attribute__((ext_vector_type(8))) short  bf16x8;  // 8 bf16 = 4 VGPR (MFMA A/B frag)
typedef __attribute__((ext_vector_type(4))) float  f32x4;   // MFMA C/D frag
typedef __attribute__((ext_vector_type(8))) u16    u16x8;
typedef __attribute__((ext_vector_type(4))) u16    u16x4;

__device__ __forceinline__ u16 f2bf(float x){            // RNE fp32 -> bf16 bits
  unsigned u = __float_as_uint(x);
  return (u16)((u + 0x7FFFu + ((u>>16)&1u)) >> 16);
}
__device__ __forceinline__ float bf2f(u16 h){ return __uint_as_float(((unsigned)h)<<16); }

// ============ init: v = 1, vT planes = (1,0), flag = 1, ctr = 0 ============
__global__ __launch_bounds__(256) void k_initv(float* __restrict__ v, u16* __restrict__ vTp,
                                               int* __restrict__ flag, unsigned* __restrict__ ctr){
  int gid = blockIdx.x*256 + threadIdx.x;               // grid 512
  #pragma unroll
  for (int i = 0; i < 4; ++i){
    int e = gid*4 + i;
    if (e < BB*16384) v[e] = 1.0f;
  }
  #pragma unroll
  for (int i = 0; i < 8; ++i){
    int e = gid*8 + i;
    if (e < BB*32768) vTp[e] = ((e>>14)&1) ? (u16)0 : (u16)0x3F80;  // hi plane=1.0, lo=0
  }
  if (gid == 0){ *flag = 1; *ctr = 0u; }
}

// ============ prep: split (no transpose)  in[128][512] -> planes [128][512] ============
__global__ __launch_bounds__(256) void k_prep(const float* __restrict__ G1, const float* __restrict__ H1,
                                              const float* __restrict__ G2, const float* __restrict__ H2,
                                              u16* __restrict__ P1p, u16* __restrict__ P2p){
  const int t = blockIdx.z, b = blockIdx.y;
  const float* src = (t==0?G1: t==1?H1: t==2?G2:H2) + (size_t)b*65536;
  u16* dst = (t<2? P1p : P2p) + ((size_t)((t&1)*BB + b))*2*65536;
  const int e0 = (blockIdx.x*256 + threadIdx.x)*8;
  float4 v0 = *(const float4*)(src + e0);
  float4 v1 = *(const float4*)(src + e0 + 4);
  float xs[8] = {v0.x,v0.y,v0.z,v0.w,v1.x,v1.y,v1.z,v1.w};
  u16x8 h, l;
  #pragma unroll
  for (int i = 0; i < 8; ++i){
    u16 hi = f2bf(xs[i]); h[i] = hi; l[i] = f2bf(xs[i] - bf2f(hi));
  }
  *(u16x8*)(dst + e0) = h;
  *(u16x8*)(dst + 65536 + e0) = l;
}

// ============ prepT: transpose + split  in[128][512] -> planes [512][128] ============
__global__ __launch_bounds__(256) void k_prepT(const float* __restrict__ H1, const float* __restrict__ G1,
                                               const float* __restrict__ H2, const float* __restrict__ G2,
                                               u16* __restrict__ Q1T, u16* __restrict__ Q2T){
  const int t = blockIdx.z & 3, b = blockIdx.z >> 2;
  const float* src = (t==0?H1: t==1?G1: t==2?H2:G2) + (size_t)b*65536;   // [128 n][512 m]
  u16* dst = (t<2? Q1T : Q2T) + ((size_t)((t&1)*BB + b))*2*65536;        // [512 m][128 n]
  const int mt = blockIdx.x*32, nt = blockIdx.y*32;
  __shared__ float ts[32][33];
  const int r = threadIdx.x>>3, c4 = (threadIdx.x&7)*4;
  float4 vv = *(const float4*)(src + (size_t)(nt+r)*512 + mt + c4);
  ts[r][c4+0]=vv.x; ts[r][c4+1]=vv.y; ts[r][c4+2]=vv.z; ts[r][c4+3]=vv.w;
  __syncthreads();
  u16x4 h, l;
  #pragma unroll
  for (int i = 0; i < 4; ++i){
    float x = ts[c4+i][r];
    u16 hi = f2bf(x); h[i] = hi; l[i] = f2bf(x - bf2f(hi));
  }
  size_t o = (size_t)(mt + r)*128 + nt + c4;
  *(u16x4*)(dst + o) = h;
  *(u16x4*)(dst + 65536 + o) = l;
}

// ============ prep MqI: transpose + split-pack Mq[b][m][q] -> u32 (hi | lo<<16) at [b][q][m] ============
__global__ __launch_bounds__(256) void k_prepM(const float* __restrict__ Mq, unsigned* __restrict__ MqI){
  const int b = blockIdx.z;
  const float* src = Mq + (size_t)b*262144;
  unsigned* D = MqI + (size_t)b*262144;
  const int mt = blockIdx.x*32, qt = blockIdx.y*32;
  __shared__ float ts[32][33];
  const int r = threadIdx.x>>3, c4 = (threadIdx.x&7)*4;
  float4 vv = *(const float4*)(src + (size_t)(mt+r)*512 + qt + c4);
  ts[r][c4+0]=vv.x; ts[r][c4+1]=vv.y; ts[r][c4+2]=vv.z; ts[r][c4+3]=vv.w;
  __syncthreads();
  uint4 pk;
  unsigned pks[4];
  #pragma unroll
  for (int i = 0; i < 4; ++i){
    float x = ts[c4+i][r];
    u16 hi = f2bf(x);
    pks[i] = (unsigned)hi | ((unsigned)f2bf(x - bf2f(hi)) << 16);
  }
  pk.x=pks[0]; pk.y=pks[1]; pk.z=pks[2]; pk.w=pks[3];
  *(uint4*)(D + (size_t)(qt + r)*512 + mt + c4) = pk;
}

// ============ S0: x1[m][p] = sum_n Q1T[m][n]*vT[p][n]   grid(512): (fb, mb of 64 rows) ============
__global__ __launch_bounds__(256) void k_s0(const u16* __restrict__ Q1T,
                                            const u16* __restrict__ vTp,
                                            u16* __restrict__ x1p,
                                            const int* __restrict__ flag){
  if (*flag == 0) return;
  const int flat = blockIdx.x;
  const int work = (flat & 7)*64 + (flat >> 3);
  const int fb = work >> 3, mb = work & 7, b = fb & 31;

  const u16* Ah = Q1T + (size_t)fb*131072 + (size_t)mb*8192;   // [64 m][128 n]
  const u16* Al = Ah + 65536;
  const u16* Bh = vTp + (size_t)b*32768;                       // [128 p][128 n]
  const u16* Bl = Bh + 16384;

  const int tid = threadIdx.x;
  const int wid = tid>>6, lane = tid&63;
  const int wn = wid*16;                    // wave owns 16 m rows x 128 p
  const int l15 = lane&15, g = lane>>4;

  __shared__ __align__(16) u16 smA[2][64*40];
  __shared__ __align__(16) u16 smB[2][128*40];

  f32x4 acc[8];
  #pragma unroll
  for (int j=0;j<8;++j) acc[j] = (f32x4){0.f,0.f,0.f,0.f};

  for (int kt = 0; kt < 128; kt += 32){
    { int row = tid>>2, seg = tid&3;
      size_t go = (size_t)row*128 + kt + seg*8;
      *(u16x8*)&smA[0][row*40 + seg*8] = *(const u16x8*)(Ah + go);
      *(u16x8*)&smA[1][row*40 + seg*8] = *(const u16x8*)(Al + go);
    }
    #pragma unroll
    for (int i = 0; i < 2; ++i){
      int c = tid + i*256, row = c>>2, seg = c&3;
      size_t go = (size_t)row*128 + kt + seg*8;
      *(u16x8*)&smB[0][row*40 + seg*8] = *(const u16x8*)(Bh + go);
      *(u16x8*)&smB[1][row*40 + seg*8] = *(const u16x8*)(Bl + go);
    }
    __syncthreads();
    bf16x8 ah = *(const bf16x8*)&smA[0][(wn + l15)*40 + g*8];
    bf16x8 al = *(const bf16x8*)&smA[1][(wn + l15)*40 + g*8];
    #pragma unroll
    for (int j=0;j<8;++j){
      bf16x8 bh = *(const bf16x8*)&smB[0][(j*16 + l15)*40 + g*8];
      bf16x8 bl = *(const bf16x8*)&smB[1][(j*16 + l15)*40 + g*8];
      acc[j] = __builtin_amdgcn_mfma_f32_16x16x32_bf16(ah, bh, acc[j], 0,0,0);
      acc[j] = __builtin_amdgcn_mfma_f32_16x16x32_bf16(al, bh, acc[j], 0,0,0);
      acc[j] = __builtin_amdgcn_mfma_f32_16x16x32_bf16(ah, bl, acc[j], 0,0,0);
    }
    __syncthreads();
  }
  u16* Ch = x1p + (size_t)fb*131072;
  u16* Cl = Ch + 65536;
  #pragma unroll
  for (int j=0;j<8;++j)
    #pragma unroll
    for (int r=0;r<4;++r){
      int ro = mb*64 + wn + g*4 + r, co = j*16 + l15;
      float x = acc[j][r];
      u16 hi = f2bf(x);
      Ch[(size_t)ro*128 + co] = hi;
      Cl[(size_t)ro*128 + co] = f2bf(x - bf2f(hi));
    }
}

// ============ S1: yB[q][m] = bf16(Mq[m][q] * sum_p Q2T[q][p]*x1[m][p])   grid(1024) ============
__global__ __launch_bounds__(256) void k_s1(const u16* __restrict__ Q2T,
                                            const u16* __restrict__ x1p,
                                            const unsigned* __restrict__ MqI,
                                            u16* __restrict__ yB,
                                            const int* __restrict__ flag){
  if (*flag == 0) return;
  const int flat = blockIdx.x;
  const int work = (flat & 7)*128 + (flat >> 3);
  const int fb = work >> 4, t = work & 15, b = fb & 31;
  const int rowBlk = (t>>2)*128, colBlk = (t&3)*128;

  const u16* Ah = Q2T + (size_t)fb*131072 + (size_t)rowBlk*128;  // [q][p] slice
  const u16* Al = Ah + 65536;
  const u16* Bh = x1p + (size_t)fb*131072 + (size_t)colBlk*128;  // [m][p] slice
  const u16* Bl = Bh + 65536;

  const int tid = threadIdx.x;
  const int wid = tid>>6, lane = tid&63;
  const int wr = (wid>>1)*64, wc = (wid&1)*64;
  const int l15 = lane&15, g = lane>>4;

  __shared__ __align__(16) u16 sm[4][128*40];
  f32x4 acc[4][4];
  #pragma unroll
  for (int i=0;i<4;++i)
    #pragma unroll
    for (int j=0;j<4;++j) acc[i][j] = (f32x4){0.f,0.f,0.f,0.f};

  u16x8 pre[4][2];
  #pragma unroll
  for (int i = 0; i < 2; ++i){
    int ch = tid*2 + i, row = ch>>2, seg = ch&3;
    size_t go = (size_t)row*128 + seg*8;
    pre[0][i] = *(const u16x8*)(Ah + go);
    pre[1][i] = *(const u16x8*)(Al + go);
    pre[2][i] = *(const u16x8*)(Bh + go);
    pre[3][i] = *(const u16x8*)(Bl + go);
  }
  for (int kt = 0; kt < 128; kt += 32){
    #pragma unroll
    for (int i = 0; i < 2; ++i){
      int ch = tid*2 + i, row = ch>>2, seg = ch&3;
      int lo = row*40 + seg*8;
      #pragma unroll
      for (int pl = 0; pl < 4; ++pl) *(u16x8*)&sm[pl][lo] = pre[pl][i];
    }
    __syncthreads();
    if (kt + 32 < 128){
      #pragma unroll
      for (int i = 0; i < 2; ++i){
        int ch = tid*2 + i, row = ch>>2, seg = ch&3;
        size_t go = (size_t)row*128 + kt + 32 + seg*8;
        pre[0][i] = *(const u16x8*)(Ah + go);
        pre[1][i] = *(const u16x8*)(Al + go);
        pre[2][i] = *(const u16x8*)(Bh + go);
        pre[3][i] = *(const u16x8*)(Bl + go);
      }
    }
    bf16x8 ah[4], al[4];
    #pragma unroll
    for (int i=0;i<4;++i){
      int r = wr + i*16 + l15;
      ah[i] = *(const bf16x8*)&sm[0][r*40 + g*8];
      al[i] = *(const bf16x8*)&sm[1][r*40 + g*8];
    }
    #pragma unroll
    for (int j=0;j<4;++j){
      int cc = wc + j*16 + l15;
      bf16x8 bh = *(const bf16x8*)&sm[2][cc*40 + g*8];
      bf16x8 bl = *(const bf16x8*)&sm[3][cc*40 + g*8];
      #pragma unroll
      for (int i=0;i<4;++i){
        acc[i][j] = __builtin_amdgcn_mfma_f32_16x16x32_bf16(ah[i], bh, acc[i][j], 0,0,0);
        acc[i][j] = __builtin_amdgcn_mfma_f32_16x16x32_bf16(al[i], bh, acc[i][j], 0,0,0);
        acc[i][j] = __builtin_amdgcn_mfma_f32_16x16x32_bf16(ah[i], bl, acc[i][j], 0,0,0);
      }
    }
    __syncthreads();
  }
  u16* Cp = yB + (size_t)fb*262144;
  const unsigned* Mqb = MqI + (size_t)b*262144;
  #pragma unroll
  for (int i=0;i<4;++i)
    #pragma unroll
    for (int j=0;j<4;++j)
      #pragma unroll
      for (int r=0;r<4;++r){
        int ro = rowBlk + wr + i*16 + g*4 + r, co = colBlk + wc + j*16 + l15;
        size_t o = (size_t)ro*512 + co;
        unsigned mq = Mqb[o];
        float mf = bf2f((u16)(mq & 0xFFFFu)) + bf2f((u16)(mq >> 16));
        float y = acc[i][j][r] * mf;
        Cp[o] = f2bf(y);                  // single bf16 plane (lo dropped; positive sums average it out)
      }
}

// ============ S2+S3 fused, n-split: per (fb,qblk,nh): z1 [64 n][128 q] in regs, then z2 chunk ============
// grid(512). y is single-plane bf16 -> 2-MFMA accumulate in S2.
__global__ __launch_bounds__(256) void k_s23(const u16* __restrict__ P1p,
                                             const u16* __restrict__ yB,
                                             const u16* __restrict__ P2p,
                                             float* __restrict__ z2p,
                                             const int* __restrict__ flag){
  if (*flag == 0) return;
  const int flat = blockIdx.x;
  const int work = (flat & 7)*64 + (flat >> 3);
  const int fb = work >> 3, qblk = (work >> 1) & 3, nh = work & 1;

  const u16* Ah = P1p + (size_t)fb*131072 + (size_t)nh*32768;   // [64 n][512 m] rows nh*64..
  const u16* Al = Ah + 65536;
  const u16* Bh = yB + (size_t)fb*262144 + (size_t)qblk*65536;  // [128 q][512 m] bf16 slice

  const int tid = threadIdx.x;
  const int wid = tid>>6, lane = tid&63;
  const int wn = wid*16;                    // wave owns 16 n rows (local) x 128 q
  const int l15 = lane&15, g = lane>>4;

  __shared__ __align__(16) u16 smA[2][64*40];
  __shared__ __align__(16) u16 smB[2][128*40];   // [0]=y (S2) / P2 hi (S3); [1]=P2 lo (S3)

  f32x4 zacc[8];
  #pragma unroll
  for (int j=0;j<8;++j) zacc[j] = (f32x4){0.f,0.f,0.f,0.f};

  // ---- S2: K=512 over m; y single-plane -> 2 MFMA ----
  for (int kt = 0; kt < 512; kt += 32){
    { int row = tid>>2, seg = tid&3;
      size_t go = (size_t)row*512 + kt + seg*8;
      *(u16x8*)&smA[0][row*40 + seg*8] = *(const u16x8*)(Ah + go);
      *(u16x8*)&smA[1][row*40 + seg*8] = *(const u16x8*)(Al + go);
    }
    #pragma unroll
    for (int i = 0; i < 2; ++i){
      int c = tid + i*256, row = c>>2, seg = c&3;
      size_t go = (size_t)row*512 + kt + seg*8;
      *(u16x8*)&smB[0][row*40 + seg*8] = *(const u16x8*)(Bh + go);
    }
    __syncthreads();
    bf16x8 ah = *(const bf16x8*)&smA[0][(wn + l15)*40 + g*8];
    bf16x8 al = *(const bf16x8*)&smA[1][(wn + l15)*40 + g*8];
    #pragma unroll
    for (int j=0;j<8;++j){
      bf16x8 bh = *(const bf16x8*)&smB[0][(j*16 + l15)*40 + g*8];
      zacc[j] = __builtin_amdgcn_mfma_f32_16x16x32_bf16(ah, bh, zacc[j], 0,0,0);
      zacc[j] = __builtin_amdgcn_mfma_f32_16x16x32_bf16(al, bh, zacc[j], 0,0,0);
    }
    __syncthreads();
  }

  // ---- S3: z2[n][p] over q-chunks of 32 (z1 regs -> LDS hi/lo, P2 hi/lo from global) ----
  f32x4 z2a[8];
  #pragma unroll
  for (int j=0;j<8;++j) z2a[j] = (f32x4){0.f,0.f,0.f,0.f};
  const u16* Ph = P2p + (size_t)fb*131072 + (size_t)qblk*128;    // [128 p][512 q] col slice
  const u16* Pl = Ph + 65536;

  #pragma unroll
  for (int c = 0; c < 4; ++c){
    #pragma unroll
    for (int jj = 0; jj < 2; ++jj)
      #pragma unroll
      for (int r = 0; r < 4; ++r){
        int n = wn + g*4 + r;
        float x = zacc[c*2 + jj][r];
        u16 hi = f2bf(x);
        smA[0][n*40 + jj*16 + l15] = hi;
        smA[1][n*40 + jj*16 + l15] = f2bf(x - bf2f(hi));
      }
    #pragma unroll
    for (int i = 0; i < 2; ++i){
      int c2 = tid + i*256, row = c2>>2, seg = c2&3;
      size_t go = (size_t)row*512 + c*32 + seg*8;
      *(u16x8*)&smB[0][row*40 + seg*8] = *(const u16x8*)(Ph + go);
      *(u16x8*)&smB[1][row*40 + seg*8] = *(const u16x8*)(Pl + go);
    }
    __syncthreads();
    bf16x8 ah = *(const bf16x8*)&smA[0][(wn + l15)*40 + g*8];
    bf16x8 al = *(const bf16x8*)&smA[1][(wn + l15)*40 + g*8];
    #pragma unroll
    for (int j=0;j<8;++j){
      bf16x8 bh = *(const bf16x8*)&smB[0][(j*16 + l15)*40 + g*8];
      bf16x8 bl = *(const bf16x8*)&smB[1][(j*16 + l15)*40 + g*8];
      z2a[j] = __builtin_amdgcn_mfma_f32_16x16x32_bf16(ah, bh, z2a[j], 0,0,0);
      z2a[j] = __builtin_amdgcn_mfma_f32_16x16x32_bf16(al, bh, z2a[j], 0,0,0);
      z2a[j] = __builtin_amdgcn_mfma_f32_16x16x32_bf16(ah, bl, z2a[j], 0,0,0);
    }
    __syncthreads();
  }

  float* Cb = z2p + ((size_t)fb*4 + qblk)*16384;
  #pragma unroll
  for (int j=0;j<8;++j)
    #pragma unroll
    for (int r=0;r<4;++r){
      int ro = nh*64 + wn + g*4 + r, co = j*16 + l15;
      Cb[(size_t)ro*128 + co] = z2a[j][r];
    }
}

// ============ fused: t = 0.5*sum(z2p) + Mp.*v ; nrm ; u ; diff ; v=u ; vT planes ; flag ============
// grid(32), block(1024)
__global__ __launch_bounds__(1024) void k_nf(const float* __restrict__ z2p,
                                             const float* __restrict__ Mp,
                                             float* __restrict__ v,
                                             u16* __restrict__ vTp,
                                             float* __restrict__ diff2,
                                             int* __restrict__ flag,
                                             unsigned* __restrict__ ctr){
  if (*flag == 0) return;
  const int b = blockIdx.x, tid = threadIdx.x;
  const size_t base = (size_t)b*16384;
  __shared__ float sred[1024];
  __shared__ float su[128][129];

  float tv[16], vv[16];
  float n2 = 0.f;
  #pragma unroll
  for (int i = 0; i < 16; ++i){
    int e = tid + i*1024;
    float z = 0.f;
    #pragma unroll
    for (int f = 0; f < 2; ++f)
      #pragma unroll
      for (int cc = 0; cc < 4; ++cc)
        z += z2p[(((size_t)f*BB + b)*4 + cc)*16384 + e];
    vv[i] = v[base + e];
    tv[i] = 0.5f*z + Mp[base + e]*vv[i];
    n2 += tv[i]*tv[i];
  }
  sred[tid] = n2; __syncthreads();
  for (int s = 512; s > 0; s >>= 1){ if (tid < s) sred[tid] += sred[tid+s]; __syncthreads(); }
  float nrm2 = sred[0];
  __syncthreads();

  float rn = (nrm2 == 0.f) ? 0.f : 1.0f / sqrtf(nrm2);
  float d2 = 0.f;
  #pragma unroll
  for (int i = 0; i < 16; ++i){
    int e = tid + i*1024;
    float u = tv[i] * rn;
    float d = u - vv[i];
    d2 += d*d;
    v[base + e] = u;
    su[e>>7][e&127] = u;
  }
  sred[tid] = d2; __syncthreads();
  for (int s = 512; s > 0; s >>= 1){ if (tid < s) sred[tid] += sred[tid+s]; __syncthreads(); }

  u16* Ch = vTp + (size_t)b*32768;
  u16* Cl = Ch + 16384;
  #pragma unroll
  for (int i = 0; i < 16; ++i){
    int e = tid + i*1024;                  // e = p*128 + n
    float x = su[e & 127][e >> 7];
    u16 hi = f2bf(x);
    Ch[e] = hi;
    Cl[e] = f2bf(x - bf2f(hi));
  }

  if (tid == 0){
    diff2[b] = sred[0];
    __threadfence();
    unsigned old = atomicAdd(ctr, 1u);
    if (old == (unsigned)(BB - 1)){
      __threadfence();
      int any = 0;
      #pragma unroll
      for (int j = 0; j < BB; ++j) any |= (diff2[j] >= EPS2) ? 1 : 0;
      if (!any) *flag = 0;
      *ctr = 0u;
    }
  }
}

extern "C" void kernel_launch(void* const* d_in, const int* in_sizes, int n_in,
                              void* d_out, int out_size, void* d_ws, size_t ws_size,
                              hipStream_t stream) {
  const float* Mp = (const float*)d_in[0];
  const float* Mq = (const float*)d_in[1];
  const float* G1 = (const float*)d_in[2];
  const float* G2 = (const float*)d_in[3];
  const float* H1 = (const float*)d_in[4];
  const float* H2 = (const float*)d_in[5];
  float* v = (float*)d_out;

  u16* Q1T = (u16*)d_ws;                   //  [64 fb][2][512][128]
  u16* Q2T = Q1T + 8388608;                //  [64 fb][2][512][128]
  u16* P1p = Q2T + 8388608;                //  [64 fb][2][128][512]
  u16* P2p = P1p + 8388608;                //  [64 fb][2][128][512]
  u16* x1p = P2p + 8388608;                //  [64 fb][2][512][128]
  u16* vTp = x1p + 8388608;                //  [32 b][2][128][128]
  unsigned* MqI = (unsigned*)(vTp + 1048576); // [32][512][512] u32 (hi|lo<<16)
  u16* yB = (u16*)(MqI + 8388608);         //  [64 fb][512 q][512 m] bf16 (single plane)
  float* z2p  = (float*)(yB + 16777216);   //  [64 fb][4 c][128][128]
  float* diff2 = z2p + 4194304;            //  [32]
  int* flag = (int*)(diff2 + 32);
  unsigned* ctr = (unsigned*)(flag + 1);

  k_initv<<<dim3(512), 256, 0, stream>>>(v, vTp, flag, ctr);
  k_prep <<<dim3(32, 32, 4),  256, 0, stream>>>(G1, H1, G2, H2, P1p, P2p);
  k_prepT<<<dim3(16, 4, 128), 256, 0, stream>>>(H1, G1, H2, G2, Q1T, Q2T);
  k_prepM<<<dim3(16, 16, 32), 256, 0, stream>>>(Mq, MqI);

  for (int it = 0; it < NITER; ++it) {
    k_s0 <<<dim3(512),  256, 0, stream>>>(Q1T, vTp, x1p, flag);
    k_s1 <<<dim3(1024), 256, 0, stream>>>(Q2T, x1p, MqI, yB, flag);
    k_s23<<<dim3(512),  256, 0, stream>>>(P1p, yB, P2p, z2p, flag);
    k_nf <<<dim3(32), 1024, 0, stream>>>(z2p, Mp, v, vTp, diff2, flag, ctr);
  }
}